// Round 20
// baseline (216.164 us; speedup 1.0000x reference)
//
#include <hip/hip_runtime.h>
#include <hip/hip_bf16.h>

#define N_NODES 100000
#define N_EDGES 1600000
#define NFEAT 128
#define NHID 128
#define NOUT 64
#define NEG_SLOPE 0.01f
#define LDA 136  // bf16 LDS row stride (272B, 16B-aligned) — used by gemm2
#define BKT_SHIFT 8
#define NBKT 391          // ceil(100000/256) buckets of 256 nodes
#define EPB_A 4096        // edges per block in fillA/bhist
#define NBA 391           // ceil(1600000/4096)
#define MAXB 6144         // LDS entry cap per bucket
#define NT64 1563         // ceil(100000/64) row tiles (gemm2)
#define GEMM_GRID 512
#define NRG 6250          // 16-row groups (100000/16 exact)
#define NTASK 12500       // rowgroups x 2 col-halves

typedef short bf16x8 __attribute__((ext_vector_type(8)));
typedef float f32x4 __attribute__((ext_vector_type(4)));
typedef float f32x2 __attribute__((ext_vector_type(2)));

__device__ __forceinline__ unsigned short f2b(float f) {
    unsigned u = __float_as_uint(f);
    unsigned r = u + 0x7FFFu + ((u >> 16) & 1u);
    return (unsigned short)(r >> 16);
}
__device__ __forceinline__ float b2f(unsigned short h) {
    return __uint_as_float(((unsigned)h) << 16);
}
__device__ __forceinline__ float lrelu(float v) {
    return v > 0.f ? v : v * NEG_SLOPE;
}
// OCP e4m3 via gfx950 HW converts
__device__ __forceinline__ unsigned char f2fp8(float f) {
    return (unsigned char)(__builtin_amdgcn_cvt_pk_fp8_f32(f, f, 0, false) & 0xFF);
}

// ---- weight fragments, pre-swizzled to MFMA order ----
// wTs[ct][ki][lane] = bf16x8 { w[k=ki*32+(lane>>4)*8+j][col=ct*16+(lane&15)] }
__global__ void k_prep(const float* __restrict__ w1, const float* __restrict__ wd,
                       const float* __restrict__ w2,
                       unsigned short* __restrict__ wTs, unsigned short* __restrict__ w2Ts) {
    int tid = blockIdx.x * 256 + threadIdx.x;
    if (tid < 3072) {
        int lane = tid & 63;
        int ki = (tid >> 6) & 3;
        int ct = tid >> 8;
        int col = ct * 16 + (lane & 15);
        int kb = ki * 32 + (lane >> 4) * 8;
        unsigned short u[8];
#pragma unroll
        for (int j = 0; j < 8; j++) {
            int k = kb + j;
            float v = (col < 128) ? w1[k * 128 + col] : wd[k * 64 + (col - 128)];
            u[j] = f2b(v);
        }
        *(bf16x8*)&wTs[tid * 8] = *(bf16x8*)u;
    }
    if (tid < 1024) {
        int lane = tid & 63;
        int ki = (tid >> 6) & 3;
        int ct = tid >> 8;
        int col = ct * 16 + (lane & 15);
        int kb = ki * 32 + (lane >> 4) * 8;
        unsigned short u[8];
#pragma unroll
        for (int j = 0; j < 8; j++) u[j] = f2b(w2[(kb + j) * 64 + col]);
        *(bf16x8*)&w2Ts[tid * 8] = *(bf16x8*)u;
    }
}

// ---- streaming convert: x fp32 -> xf bf16 in A-fragment layout ----
// chunk c handles (row = c>>4, k = (c&15)*8 .. +8); dst frag slot
// (rg*4 + ki)*64 + (kc&3)*16 + (row&15), elements j = k&7.
__global__ __launch_bounds__(256) void k_conv(const float* __restrict__ x,
                                              unsigned short* __restrict__ xf) {
    int c = blockIdx.x * 256 + threadIdx.x;   // 0 .. 1.6M-1 (exact)
    int row = c >> 4, kc = c & 15;
    const float* sp = &x[(size_t)row * 128 + kc * 8];
    float4 v0 = *(const float4*)&sp[0];
    float4 v1 = *(const float4*)&sp[4];
    unsigned short u[8];
    u[0] = f2b(v0.x); u[1] = f2b(v0.y); u[2] = f2b(v0.z); u[3] = f2b(v0.w);
    u[4] = f2b(v1.x); u[5] = f2b(v1.y); u[6] = f2b(v1.z); u[7] = f2b(v1.w);
    int rg = row >> 4, ki = kc >> 2;
    int lanep = (kc & 3) * 16 + (row & 15);
    *(bf16x8*)&xf[((size_t)(rg * 4 + ki) * 64 + lanep) * 8] = *(bf16x8*)u;
}

// ---- bucket-level histogram (391 bins, LDS-aggregated) ----
__global__ __launch_bounds__(256) void k_bhist(const int* __restrict__ dst,
                                               int* __restrict__ bcnt) {
    __shared__ int lcnt[NBKT];
    const int t = threadIdx.x;
    const int e0 = blockIdx.x * EPB_A;
    const int nd = min(EPB_A, N_EDGES - e0);
    for (int i = t; i < NBKT; i += 256) lcnt[i] = 0;
    __syncthreads();
    for (int i = t; i < nd; i += 256) {
        int d = dst[e0 + i];
        atomicAdd(&lcnt[d >> BKT_SHIFT], 1);
    }
    __syncthreads();
    for (int i = t; i < NBKT; i += 256)
        if (lcnt[i]) atomicAdd(&bcnt[i], lcnt[i]);
}

// ---- scan of bucket counts -> bucket bases + cursors (single block) ----
__global__ __launch_bounds__(512) void k_bscan(const int* __restrict__ bcnt,
                                               int* __restrict__ bbase,
                                               int* __restrict__ bcur) {
    __shared__ int sc[512];
    int t = threadIdx.x;
    int v = (t < NBKT) ? bcnt[t] : 0;
    sc[t] = v;
    __syncthreads();
    for (int off = 1; off < 512; off <<= 1) {
        int xv = (t >= off) ? sc[t - off] : 0;
        __syncthreads();
        sc[t] += xv;
        __syncthreads();
    }
    if (t < NBKT) {
        int base = sc[t] - v;
        bbase[t] = base;
        bcur[t] = base;
    }
}

// ---- fillA: coarse bucket scatter of {src, dst} ----
__global__ __launch_bounds__(256) void k_fillA(const int* __restrict__ src,
                                               const int* __restrict__ dst,
                                               int* __restrict__ bcur,
                                               uint2* __restrict__ csr) {
    __shared__ int lcnt[NBKT];
    __shared__ int lbase[NBKT];
    const int t = threadIdx.x;
    const int e0 = blockIdx.x * EPB_A;
    const int nd = min(EPB_A, N_EDGES - e0);
    for (int i = t; i < NBKT; i += 256) lcnt[i] = 0;
    __syncthreads();
    for (int i = t; i < nd; i += 256) {
        int d = dst[e0 + i];
        atomicAdd(&lcnt[d >> BKT_SHIFT], 1);
    }
    __syncthreads();
    for (int i = t; i < NBKT; i += 256)
        lbase[i] = lcnt[i] ? atomicAdd(&bcur[i], lcnt[i]) : 0;
    __syncthreads();
    for (int i = t; i < NBKT; i += 256) lcnt[i] = 0;
    __syncthreads();
    for (int i = t; i < nd; i += 256) {
        int s = src[e0 + i];
        int d = dst[e0 + i];
        int b = d >> BKT_SHIFT;
        int off = atomicAdd(&lcnt[b], 1);
        csr[lbase[b] + off] = make_uint2((unsigned)s, (unsigned)d);
    }
}

// ---- fillB1: per-bucket node counts -> rowptr + dinv (no global atomics) ----
__global__ __launch_bounds__(256) void k_fillB1(const uint2* __restrict__ csr,
                                                const int* __restrict__ bbase,
                                                const int* __restrict__ bcnt,
                                                int* __restrict__ rowptr,
                                                float* __restrict__ dinv) {
    __shared__ int lcnt[256];
    __shared__ int sc[256];
    const int t = threadIdx.x;
    const int b = blockIdx.x;
    const int n0 = b << BKT_SHIFT;
    const int n1 = min(n0 + 256, N_NODES);
    const int R0 = bbase[b];
    const int cntE = bcnt[b];
    lcnt[t] = 0;
    __syncthreads();
    for (int i = t; i < cntE; i += 256) {
        uint2 e = csr[R0 + i];
        atomicAdd(&lcnt[(int)e.y & 255], 1);
    }
    __syncthreads();
    int myc = lcnt[t];
    sc[t] = myc;
    __syncthreads();
    for (int off = 1; off < 256; off <<= 1) {
        int xv = (t >= off) ? sc[t - off] : 0;
        __syncthreads();
        sc[t] += xv;
        __syncthreads();
    }
    if (n0 + t < n1) {
        rowptr[n0 + t] = R0 + sc[t] - myc;
        dinv[n0 + t] = rsqrtf((float)(myc + 1));
    }
    if (b == NBKT - 1 && t == 0) rowptr[N_NODES] = N_EDGES;
}

// ---- fillB2: in-place fine permutation within each bucket ----
__global__ __launch_bounds__(256) void k_fillB2(const float* __restrict__ dinv,
                                                const int* __restrict__ rowptr,
                                                uint2* __restrict__ csr) {
    __shared__ uint2 lbuf[MAXB];
    __shared__ int lcur[256];
    __shared__ int lrp[256];
    const int t = threadIdx.x;
    const int b = blockIdx.x;
    const int n0 = b << BKT_SHIFT;
    const int n1 = min(n0 + 256, N_NODES);
    const int R0 = rowptr[n0], R1 = rowptr[n1];
    const int cnt = R1 - R0;
    for (int i = t; i < cnt; i += 256) lbuf[i] = csr[R0 + i];
    if (n0 + t < n1) lrp[t] = rowptr[n0 + t];
    lcur[t] = 0;
    __syncthreads();  // all region reads complete before any region write
    for (int i = t; i < cnt; i += 256) {
        uint2 e = lbuf[i];
        int li = (int)e.y & 255;
        int r = atomicAdd(&lcur[li], 1);
        int p = lrp[li] + r;
        csr[p] = make_uint2(e.x, __float_as_uint(dinv[e.x]));
    }
}

// ---- GEMM1, fragment-direct: NO LDS, NO syncthreads ----
// wave = one 16-row group x 96 cols (wc = task&1); A-frags wave-contiguous
// from xf; B persistent (grid-stride keeps wc invariant). Waves fully
// independent -> loads pipeline across tasks, no phase serialization.
__global__ __launch_bounds__(256, 1) void k_gemm1f(const unsigned short* __restrict__ xf,
                                                   const unsigned short* __restrict__ wTs,
                                                   const float* __restrict__ bd,
                                                   unsigned char* __restrict__ h1,
                                                   float* __restrict__ identity) {
    const int wid = threadIdx.x >> 6, lane = threadIdx.x & 63;
    const int task0 = blockIdx.x * 4 + wid;
    const int wc = task0 & 1;
    const int nc = wc * 96;
    const int lrow = lane & 15;
    const int crow0 = (lane >> 4) * 4;
    bf16x8 b[6][4];
#pragma unroll
    for (int n = 0; n < 6; n++)
#pragma unroll
        for (int ki = 0; ki < 4; ki++)
            b[n][ki] = *(const bf16x8*)&wTs[(((wc * 6 + n) * 4 + ki) * 64 + lane) * 8];

    for (int task = task0; task < NTASK; task += GEMM_GRID * 4) {
        const int rg = task >> 1;
        bf16x8 a[4];
#pragma unroll
        for (int ki = 0; ki < 4; ki++)
            a[ki] = *(const bf16x8*)&xf[((size_t)(rg * 4 + ki) * 64 + lane) * 8];
        f32x4 acc[6];
#pragma unroll
        for (int n = 0; n < 6; n++) acc[n] = (f32x4){0.f, 0.f, 0.f, 0.f};
#pragma unroll
        for (int n = 0; n < 6; n++)
#pragma unroll
            for (int ki = 0; ki < 4; ki++)
                acc[n] = __builtin_amdgcn_mfma_f32_16x16x32_bf16(a[ki], b[n][ki], acc[n], 0, 0, 0);
#pragma unroll
        for (int j = 0; j < 4; j++) {
            int grow = rg * 16 + crow0 + j;   // always < N_NODES (100000 = 6250*16)
#pragma unroll
            for (int n = 0; n < 6; n++) {
                int col = nc + n * 16 + lrow;
                float v = acc[n][j];
                if (col < 128) h1[(size_t)grow * 128 + col] = f2fp8(v);
                else           identity[(size_t)grow * 64 + (col - 128)] = v + bd[col - 128];
            }
        }
    }
}

// ---- MFMA GEMM2: h2 = fp8(out1 @ w2) (LDS version, unchanged) ----
__global__ __launch_bounds__(256, 1) void k_gemm2(const unsigned short* __restrict__ a_in,
                                                  const unsigned short* __restrict__ w2Ts,
                                                  unsigned char* __restrict__ h2) {
    __shared__ unsigned short As[64][LDA];
    const int t = threadIdx.x;
    const int wid = t >> 6, lane = t & 63;
    const int wr = wid >> 1, wc = wid & 1;
    const int mr = wr * 32, nc = wc * 32;
    const int lrow = lane & 15;
    bf16x8 b[2][4];
#pragma unroll
    for (int n = 0; n < 2; n++)
#pragma unroll
        for (int ki = 0; ki < 4; ki++)
            b[n][ki] = *(const bf16x8*)&w2Ts[(((wc * 2 + n) * 4 + ki) * 64 + lane) * 8];

    for (int tile = blockIdx.x; tile < NT64; tile += GEMM_GRID) {
        const int rb = tile * 64;
        __syncthreads();
        {
#pragma unroll
            for (int i = 0; i < 4; i++) {
                int c = i * 256 + t;         // 16B bf16 chunk id; lane-contiguous
                int row = c >> 4, off = c & 15;
                bf16x8 v = (bf16x8){0, 0, 0, 0, 0, 0, 0, 0};
                if (rb + row < N_NODES)
                    v = *(const bf16x8*)&a_in[(size_t)(rb + row) * 128 + off * 8];
                *(bf16x8*)&As[row][off * 8] = v;
            }
        }
        __syncthreads();
        const int lk = (lane >> 4) * 8;
        bf16x8 a[4][2];
#pragma unroll
        for (int ki = 0; ki < 4; ki++)
#pragma unroll
            for (int m = 0; m < 2; m++)
                a[ki][m] = *(const bf16x8*)&As[mr + m * 16 + lrow][ki * 32 + lk];
        f32x4 acc[2][2];
#pragma unroll
        for (int m = 0; m < 2; m++)
#pragma unroll
            for (int n = 0; n < 2; n++) acc[m][n] = (f32x4){0.f, 0.f, 0.f, 0.f};
#pragma unroll
        for (int n = 0; n < 2; n++)
#pragma unroll
            for (int ki = 0; ki < 4; ki++)
#pragma unroll
                for (int m = 0; m < 2; m++)
                    acc[m][n] = __builtin_amdgcn_mfma_f32_16x16x32_bf16(a[ki][m], b[n][ki], acc[m][n], 0, 0, 0);
        const int crow0 = (lane >> 4) * 4;
#pragma unroll
        for (int m = 0; m < 2; m++) {
#pragma unroll
            for (int j = 0; j < 4; j++) {
                int grow = rb + mr + m * 16 + crow0 + j;
                if (grow >= N_NODES) continue;
#pragma unroll
                for (int n = 0; n < 2; n++) {
                    int col = nc + n * 16 + lrow;
                    h2[(size_t)grow * 64 + col] = f2fp8(acc[m][n][j]);
                }
            }
        }
    }
}

// ---- aggregate 1: out1 = leaky(di*(sum_e dinv_s*h1[src] + di*h1[i]) + b1) ----
// wave = 1 node; 8 groups x 8 lanes; reduce-scatter butterfly + distributed epilogue
__global__ __launch_bounds__(256) void k_agg1(const unsigned char* __restrict__ h1,
                                              const uint2* __restrict__ csr,
                                              const int* __restrict__ rowptr,
                                              const float* __restrict__ dinv,
                                              const float* __restrict__ b1,
                                              unsigned short* __restrict__ out1) {
    int node = blockIdx.x * 4 + (threadIdx.x >> 6);
    if (node >= N_NODES) return;
    const int lane = threadIdx.x & 63;
    const int g = lane >> 3;   // edge slot 0..7
    const int l = lane & 7;    // feature chunk: [l*16, l*16+16)
    const float di = dinv[node];
    f32x2 a2[8];
#pragma unroll
    for (int i = 0; i < 8; i++) a2[i] = (f32x2){0.f, 0.f};
    const int beg = rowptr[node], end = rowptr[node + 1];
    uint2 ce = csr[beg + g];                 // csr padded with 16 zeroed entries
    for (int e0 = beg; e0 < end; e0 += 8) {
        uint2 ce_n = csr[e0 + 8 + g];        // prefetch next iteration's entry
        int e = e0 + g;
        if (e < end) {
            float w = __uint_as_float(ce.y);  // dinv[src]; di folded into epilogue
            f32x2 w2 = (f32x2){w, w};
            uint4 h = *(const uint4*)&h1[(size_t)ce.x * 128 + l * 16];
            a2[0] = __builtin_elementwise_fma(w2, __builtin_amdgcn_cvt_pk_f32_fp8(h.x, false), a2[0]);
            a2[1] = __builtin_elementwise_fma(w2, __builtin_amdgcn_cvt_pk_f32_fp8(h.x, true),  a2[1]);
            a2[2] = __builtin_elementwise_fma(w2, __builtin_amdgcn_cvt_pk_f32_fp8(h.y, false), a2[2]);
            a2[3] = __builtin_elementwise_fma(w2, __builtin_amdgcn_cvt_pk_f32_fp8(h.y, true),  a2[3]);
            a2[4] = __builtin_elementwise_fma(w2, __builtin_amdgcn_cvt_pk_f32_fp8(h.z, false), a2[4]);
            a2[5] = __builtin_elementwise_fma(w2, __builtin_amdgcn_cvt_pk_f32_fp8(h.z, true),  a2[5]);
            a2[6] = __builtin_elementwise_fma(w2, __builtin_amdgcn_cvt_pk_f32_fp8(h.w, false), a2[6]);
            a2[7] = __builtin_elementwise_fma(w2, __builtin_amdgcn_cvt_pk_f32_fp8(h.w, true),  a2[7]);
        }
        ce = ce_n;
    }
    // reduce-scatter butterfly over group bits g2 (xor32), g1 (xor16), g0 (xor8)
    const bool s2 = (lane & 32) != 0;
    const bool s1 = (lane & 16) != 0;
    const bool s0 = (lane & 8) != 0;
    f32x2 rA[4];
#pragma unroll
    for (int j = 0; j < 4; j++) {
        f32x2 keep = s2 ? a2[j + 4] : a2[j];
        f32x2 send = s2 ? a2[j] : a2[j + 4];
        rA[j].x = keep.x + __shfl_xor(send.x, 32);
        rA[j].y = keep.y + __shfl_xor(send.y, 32);
    }
    f32x2 rB[2];
#pragma unroll
    for (int j = 0; j < 2; j++) {
        f32x2 keep = s1 ? rA[j + 2] : rA[j];
        f32x2 send = s1 ? rA[j] : rA[j + 2];
        rB[j].x = keep.x + __shfl_xor(send.x, 16);
        rB[j].y = keep.y + __shfl_xor(send.y, 16);
    }
    f32x2 rC;
    {
        f32x2 keep = s0 ? rB[1] : rB[0];
        f32x2 send = s0 ? rB[0] : rB[1];
        rC.x = keep.x + __shfl_xor(send.x, 8);
        rC.y = keep.y + __shfl_xor(send.y, 8);
    }
    // distributed epilogue: this lane owns feats f0, f0+1 with values rC
    {
        const int f0 = l * 16 + g * 2;
        unsigned hs = (unsigned)*(const unsigned short*)&h1[(size_t)node * 128 + f0];
        f32x2 sv = __builtin_amdgcn_cvt_pk_f32_fp8(hs, false);
        float2 bb = *(const float2*)&b1[f0];
        float t0 = rC.x + di * sv.x;
        float t1 = rC.y + di * sv.y;
        float o0 = lrelu(fmaf(t0, di, bb.x));
        float o1 = lrelu(fmaf(t1, di, bb.y));
        unsigned ov = (unsigned)f2b(o0) | ((unsigned)f2b(o1) << 16);
        *(unsigned*)&out1[(size_t)node * 128 + f0] = ov;
    }
}

// ---- aggregate 2 + epilogue: out = leaky(di*(agg + di*h_self) + b2) + identity ----
// wave = 1 node; 8 groups x 8 lanes; reduce-scatter; lane (g,l) writes feat l*8+g
__global__ __launch_bounds__(256) void k_agg2(const unsigned char* __restrict__ h2,
                                              const uint2* __restrict__ csr,
                                              const int* __restrict__ rowptr,
                                              const float* __restrict__ dinv,
                                              const float* __restrict__ b2,
                                              const float* __restrict__ identity,
                                              float* __restrict__ out) {
    int node = blockIdx.x * 4 + (threadIdx.x >> 6);
    if (node >= N_NODES) return;
    const int lane = threadIdx.x & 63;
    const int g = lane >> 3;
    const int l = lane & 7;    // feature chunk: [l*8, l*8+8)
    const float di = dinv[node];
    f32x2 a2[4];
#pragma unroll
    for (int i = 0; i < 4; i++) a2[i] = (f32x2){0.f, 0.f};
    const int beg = rowptr[node], end = rowptr[node + 1];
    uint2 ce = csr[beg + g];
    for (int e0 = beg; e0 < end; e0 += 8) {
        uint2 ce_n = csr[e0 + 8 + g];
        int e = e0 + g;
        if (e < end) {
            float w = __uint_as_float(ce.y);  // dinv[src]
            f32x2 w2 = (f32x2){w, w};
            uint2 h = *(const uint2*)&h2[(size_t)ce.x * 64 + l * 8];
            a2[0] = __builtin_elementwise_fma(w2, __builtin_amdgcn_cvt_pk_f32_fp8(h.x, false), a2[0]);
            a2[1] = __builtin_elementwise_fma(w2, __builtin_amdgcn_cvt_pk_f32_fp8(h.x, true),  a2[1]);
            a2[2] = __builtin_elementwise_fma(w2, __builtin_amdgcn_cvt_pk_f32_fp8(h.y, false), a2[2]);
            a2[3] = __builtin_elementwise_fma(w2, __builtin_amdgcn_cvt_pk_f32_fp8(h.y, true),  a2[3]);
        }
        ce = ce_n;
    }
    float a[8];
#pragma unroll
    for (int i = 0; i < 4; i++) { a[2 * i] = a2[i].x; a[2 * i + 1] = a2[i].y; }
    // reduce-scatter over group bits
    const bool s2 = (lane & 32) != 0;
    const bool s1 = (lane & 16) != 0;
    const bool s0 = (lane & 8) != 0;
    float kA[4];
#pragma unroll
    for (int j = 0; j < 4; j++) {
        float keep = s2 ? a[j + 4] : a[j];
        float send = s2 ? a[j] : a[j + 4];
        kA[j] = keep + __shfl_xor(send, 32);
    }
    float kB[2];
#pragma unroll
    for (int j = 0; j < 2; j++) {
        float keep = s1 ? kA[j + 2] : kA[j];
        float send = s1 ? kA[j] : kA[j + 2];
        kB[j] = keep + __shfl_xor(send, 16);
    }
    float kC;
    {
        float keep = s0 ? kB[1] : kB[0];
        float send = s0 ? kB[0] : kB[1];
        kC = keep + __shfl_xor(send, 8);
    }
    // distributed epilogue: this lane owns feat f0 = l*8 + g with value kC
    {
        const int f0 = l * 8 + g;
        unsigned c = (unsigned)h2[(size_t)node * 64 + f0];
        f32x2 svv = __builtin_amdgcn_cvt_pk_f32_fp8(c, false);
        float sv = svv.x;
        float t = kC + di * sv;
        float o = lrelu(fmaf(t, di, b2[f0])) + identity[(size_t)node * 64 + f0];
        out[(size_t)node * 64 + f0] = o;
    }
}

extern "C" void kernel_launch(void* const* d_in, const int* in_sizes, int n_in,
                              void* d_out, int out_size, void* d_ws, size_t ws_size,
                              hipStream_t stream) {
    const float* x  = (const float*)d_in[0];
    const int* eidx = (const int*)d_in[1];
    const float* w1 = (const float*)d_in[2];
    const float* b1 = (const float*)d_in[3];
    const float* w2 = (const float*)d_in[4];
    const float* b2 = (const float*)d_in[5];
    const float* wd = (const float*)d_in[6];
    const float* bd = (const float*)d_in[7];
    const int* src = eidx;
    const int* dst = eidx + N_EDGES;
    float* out = (float*)d_out;

    char* ws = (char*)d_ws;
    size_t off = 0;
    auto take = [&](size_t bytes) -> char* {
        char* p = ws + off;
        off = (off + bytes + 255) & ~(size_t)255;
        return p;
    };
    int* bcnt       = (int*)take((size_t)NBKT * 4);
    int* bbase      = (int*)take((size_t)NBKT * 4);
    int* bcur       = (int*)take((size_t)NBKT * 4);
    int* rowptr     = (int*)take((size_t)(N_NODES + 1) * 4);
    float* dinv     = (float*)take((size_t)N_NODES * 4);
    uint2* csr      = (uint2*)take((size_t)(N_EDGES + 16) * 8);  // +16 zeroed pad entries
    unsigned char* h1   = (unsigned char*)take((size_t)N_NODES * 128);
    unsigned short* out1 = (unsigned short*)take((size_t)N_NODES * 128 * 2);
    unsigned char* h2   = (unsigned char*)take((size_t)N_NODES * 64);
    float* identity = (float*)take((size_t)N_NODES * 64 * 4);
    unsigned short* xf   = (unsigned short*)take((size_t)N_NODES * 128 * 2);
    unsigned short* wTs  = (unsigned short*)take((size_t)3072 * 8 * 2);
    unsigned short* w2Ts = (unsigned short*)take((size_t)1024 * 8 * 2);

    hipMemsetAsync(bcnt, 0, (size_t)NBKT * 4, stream);
    hipMemsetAsync(csr + N_EDGES, 0, 16 * sizeof(uint2), stream);

    k_prep<<<12, 256, 0, stream>>>(w1, wd, w2, wTs, w2Ts);
    k_conv<<<NRG, 256, 0, stream>>>(x, xf);
    k_bhist<<<NBA, 256, 0, stream>>>(dst, bcnt);
    k_bscan<<<1, 512, 0, stream>>>(bcnt, bbase, bcur);
    k_fillA<<<NBA, 256, 0, stream>>>(src, dst, bcur, csr);
    k_fillB1<<<NBKT, 256, 0, stream>>>(csr, bbase, bcnt, rowptr, dinv);
    k_fillB2<<<NBKT, 256, 0, stream>>>(dinv, rowptr, csr);
    k_gemm1f<<<GEMM_GRID, 256, 0, stream>>>(xf, wTs, bd, h1, identity);
    k_agg1<<<(N_NODES + 3) / 4, 256, 0, stream>>>(h1, csr, rowptr, dinv, b1, out1);
    k_gemm2<<<GEMM_GRID, 256, 0, stream>>>(out1, w2Ts, h2);
    k_agg2<<<(N_NODES + 3) / 4, 256, 0, stream>>>(h2, csr, rowptr, dinv, b2, identity, out);
}

// Round 21
// 212.408 us; speedup vs baseline: 1.0177x; 1.0177x over previous
//
#include <hip/hip_runtime.h>
#include <hip/hip_bf16.h>

#define N_NODES 100000
#define N_EDGES 1600000
#define NFEAT 128
#define NHID 128
#define NOUT 64
#define NEG_SLOPE 0.01f
#define LDA 136  // bf16 LDS row stride (272B, 16B-aligned) — used by gemm2
#define BKT_SHIFT 8
#define NBKT 391          // ceil(100000/256) buckets of 256 nodes
#define EPB_A 4096        // edges per block in fillA/bhist
#define NBA 391           // ceil(1600000/4096)
#define MAXB 6144         // LDS entry cap per bucket
#define NT64 1563         // ceil(100000/64) row tiles (gemm2)
#define GEMM_GRID 512
#define NRG 6250          // 16-row groups (100000/16 exact)
#define NTASK 12500       // rowgroups x 2 col-halves

typedef short bf16x8 __attribute__((ext_vector_type(8)));
typedef float f32x4 __attribute__((ext_vector_type(4)));
typedef float f32x2 __attribute__((ext_vector_type(2)));

__device__ __forceinline__ unsigned short f2b(float f) {
    unsigned u = __float_as_uint(f);
    unsigned r = u + 0x7FFFu + ((u >> 16) & 1u);
    return (unsigned short)(r >> 16);
}
__device__ __forceinline__ float b2f(unsigned short h) {
    return __uint_as_float(((unsigned)h) << 16);
}
__device__ __forceinline__ float lrelu(float v) {
    return v > 0.f ? v : v * NEG_SLOPE;
}
// OCP e4m3 via gfx950 HW converts
__device__ __forceinline__ unsigned char f2fp8(float f) {
    return (unsigned char)(__builtin_amdgcn_cvt_pk_fp8_f32(f, f, 0, false) & 0xFF);
}

// ---- fused pre-pass: conv (blocks 0..NRG) | bhist (next NBA) | prep (last 12) ----
__global__ __launch_bounds__(256) void k_pre(const float* __restrict__ x,
                                             unsigned short* __restrict__ xf,
                                             const int* __restrict__ dst,
                                             int* __restrict__ bcnt,
                                             const float* __restrict__ w1,
                                             const float* __restrict__ wd,
                                             const float* __restrict__ w2,
                                             unsigned short* __restrict__ wTs,
                                             unsigned short* __restrict__ w2Ts) {
    const int bid = blockIdx.x;
    const int t = threadIdx.x;
    if (bid < NRG) {
        // streaming convert x fp32 -> xf bf16 in A-fragment layout
        int c = bid * 256 + t;   // 0 .. 1.6M-1 exact
        int row = c >> 4, kc = c & 15;
        const float* sp = &x[(size_t)row * 128 + kc * 8];
        float4 v0 = *(const float4*)&sp[0];
        float4 v1 = *(const float4*)&sp[4];
        unsigned short u[8];
        u[0] = f2b(v0.x); u[1] = f2b(v0.y); u[2] = f2b(v0.z); u[3] = f2b(v0.w);
        u[4] = f2b(v1.x); u[5] = f2b(v1.y); u[6] = f2b(v1.z); u[7] = f2b(v1.w);
        int rg = row >> 4, ki = kc >> 2;
        int lanep = (kc & 3) * 16 + (row & 15);
        *(bf16x8*)&xf[((size_t)(rg * 4 + ki) * 64 + lanep) * 8] = *(bf16x8*)u;
    } else if (bid < NRG + NBA) {
        // bucket-level histogram
        __shared__ int lcnt[NBKT];
        const int e0 = (bid - NRG) * EPB_A;
        const int nd = min(EPB_A, N_EDGES - e0);
        for (int i = t; i < NBKT; i += 256) lcnt[i] = 0;
        __syncthreads();
        for (int i = t; i < nd; i += 256) {
            int d = dst[e0 + i];
            atomicAdd(&lcnt[d >> BKT_SHIFT], 1);
        }
        __syncthreads();
        for (int i = t; i < NBKT; i += 256)
            if (lcnt[i]) atomicAdd(&bcnt[i], lcnt[i]);
    } else {
        // weight fragments pre-swizzle
        int tid = (bid - NRG - NBA) * 256 + t;
        if (tid < 3072) {
            int lane = tid & 63;
            int ki = (tid >> 6) & 3;
            int ct = tid >> 8;
            int col = ct * 16 + (lane & 15);
            int kb = ki * 32 + (lane >> 4) * 8;
            unsigned short u[8];
#pragma unroll
            for (int j = 0; j < 8; j++) {
                int k = kb + j;
                float v = (col < 128) ? w1[k * 128 + col] : wd[k * 64 + (col - 128)];
                u[j] = f2b(v);
            }
            *(bf16x8*)&wTs[tid * 8] = *(bf16x8*)u;
        }
        if (tid < 1024) {
            int lane = tid & 63;
            int ki = (tid >> 6) & 3;
            int ct = tid >> 8;
            int col = ct * 16 + (lane & 15);
            int kb = ki * 32 + (lane >> 4) * 8;
            unsigned short u[8];
#pragma unroll
            for (int j = 0; j < 8; j++) u[j] = f2b(w2[(kb + j) * 64 + col]);
            *(bf16x8*)&w2Ts[tid * 8] = *(bf16x8*)u;
        }
    }
}

// ---- scan of bucket counts -> bucket bases + cursors (single block) ----
__global__ __launch_bounds__(512) void k_bscan(const int* __restrict__ bcnt,
                                               int* __restrict__ bbase,
                                               int* __restrict__ bcur) {
    __shared__ int sc[512];
    int t = threadIdx.x;
    int v = (t < NBKT) ? bcnt[t] : 0;
    sc[t] = v;
    __syncthreads();
    for (int off = 1; off < 512; off <<= 1) {
        int xv = (t >= off) ? sc[t - off] : 0;
        __syncthreads();
        sc[t] += xv;
        __syncthreads();
    }
    if (t < NBKT) {
        int base = sc[t] - v;
        bbase[t] = base;
        bcur[t] = base;
    }
}

// ---- fillA: coarse bucket scatter of {src, dst} ----
__global__ __launch_bounds__(256) void k_fillA(const int* __restrict__ src,
                                               const int* __restrict__ dst,
                                               int* __restrict__ bcur,
                                               uint2* __restrict__ csr) {
    __shared__ int lcnt[NBKT];
    __shared__ int lbase[NBKT];
    const int t = threadIdx.x;
    const int e0 = blockIdx.x * EPB_A;
    const int nd = min(EPB_A, N_EDGES - e0);
    for (int i = t; i < NBKT; i += 256) lcnt[i] = 0;
    __syncthreads();
    for (int i = t; i < nd; i += 256) {
        int d = dst[e0 + i];
        atomicAdd(&lcnt[d >> BKT_SHIFT], 1);
    }
    __syncthreads();
    for (int i = t; i < NBKT; i += 256)
        lbase[i] = lcnt[i] ? atomicAdd(&bcur[i], lcnt[i]) : 0;
    __syncthreads();
    for (int i = t; i < NBKT; i += 256) lcnt[i] = 0;
    __syncthreads();
    for (int i = t; i < nd; i += 256) {
        int s = src[e0 + i];
        int d = dst[e0 + i];
        int b = d >> BKT_SHIFT;
        int off = atomicAdd(&lcnt[b], 1);
        csr[lbase[b] + off] = make_uint2((unsigned)s, (unsigned)d);
    }
}

// ---- fillB1: per-bucket node counts -> rowptr + dinv (no global atomics) ----
__global__ __launch_bounds__(256) void k_fillB1(const uint2* __restrict__ csr,
                                                const int* __restrict__ bbase,
                                                const int* __restrict__ bcnt,
                                                int* __restrict__ rowptr,
                                                float* __restrict__ dinv) {
    __shared__ int lcnt[256];
    __shared__ int sc[256];
    const int t = threadIdx.x;
    const int b = blockIdx.x;
    const int n0 = b << BKT_SHIFT;
    const int n1 = min(n0 + 256, N_NODES);
    const int R0 = bbase[b];
    const int cntE = bcnt[b];
    lcnt[t] = 0;
    __syncthreads();
    for (int i = t; i < cntE; i += 256) {
        uint2 e = csr[R0 + i];
        atomicAdd(&lcnt[(int)e.y & 255], 1);
    }
    __syncthreads();
    int myc = lcnt[t];
    sc[t] = myc;
    __syncthreads();
    for (int off = 1; off < 256; off <<= 1) {
        int xv = (t >= off) ? sc[t - off] : 0;
        __syncthreads();
        sc[t] += xv;
        __syncthreads();
    }
    if (n0 + t < n1) {
        rowptr[n0 + t] = R0 + sc[t] - myc;
        dinv[n0 + t] = rsqrtf((float)(myc + 1));
    }
    if (b == NBKT - 1 && t == 0) rowptr[N_NODES] = N_EDGES;
}

// ---- fillB2: in-place fine permutation within each bucket ----
__global__ __launch_bounds__(256) void k_fillB2(const float* __restrict__ dinv,
                                                const int* __restrict__ rowptr,
                                                uint2* __restrict__ csr) {
    __shared__ uint2 lbuf[MAXB];
    __shared__ int lcur[256];
    __shared__ int lrp[256];
    const int t = threadIdx.x;
    const int b = blockIdx.x;
    const int n0 = b << BKT_SHIFT;
    const int n1 = min(n0 + 256, N_NODES);
    const int R0 = rowptr[n0], R1 = rowptr[n1];
    const int cnt = R1 - R0;
    for (int i = t; i < cnt; i += 256) lbuf[i] = csr[R0 + i];
    if (n0 + t < n1) lrp[t] = rowptr[n0 + t];
    lcur[t] = 0;
    __syncthreads();  // all region reads complete before any region write
    for (int i = t; i < cnt; i += 256) {
        uint2 e = lbuf[i];
        int li = (int)e.y & 255;
        int r = atomicAdd(&lcur[li], 1);
        int p = lrp[li] + r;
        csr[p] = make_uint2(e.x, __float_as_uint(dinv[e.x]));
    }
}

// ---- GEMM1, fragment-direct: NO LDS, NO syncthreads ----
__global__ __launch_bounds__(256, 1) void k_gemm1f(const unsigned short* __restrict__ xf,
                                                   const unsigned short* __restrict__ wTs,
                                                   const float* __restrict__ bd,
                                                   unsigned char* __restrict__ h1,
                                                   float* __restrict__ identity) {
    const int wid = threadIdx.x >> 6, lane = threadIdx.x & 63;
    const int task0 = blockIdx.x * 4 + wid;
    const int wc = task0 & 1;
    const int nc = wc * 96;
    const int lrow = lane & 15;
    const int crow0 = (lane >> 4) * 4;
    bf16x8 b[6][4];
#pragma unroll
    for (int n = 0; n < 6; n++)
#pragma unroll
        for (int ki = 0; ki < 4; ki++)
            b[n][ki] = *(const bf16x8*)&wTs[(((wc * 6 + n) * 4 + ki) * 64 + lane) * 8];

    for (int task = task0; task < NTASK; task += GEMM_GRID * 4) {
        const int rg = task >> 1;
        bf16x8 a[4];
#pragma unroll
        for (int ki = 0; ki < 4; ki++)
            a[ki] = *(const bf16x8*)&xf[((size_t)(rg * 4 + ki) * 64 + lane) * 8];
        f32x4 acc[6];
#pragma unroll
        for (int n = 0; n < 6; n++) acc[n] = (f32x4){0.f, 0.f, 0.f, 0.f};
#pragma unroll
        for (int n = 0; n < 6; n++)
#pragma unroll
            for (int ki = 0; ki < 4; ki++)
                acc[n] = __builtin_amdgcn_mfma_f32_16x16x32_bf16(a[ki], b[n][ki], acc[n], 0, 0, 0);
#pragma unroll
        for (int j = 0; j < 4; j++) {
            int grow = rg * 16 + crow0 + j;   // always < N_NODES
#pragma unroll
            for (int n = 0; n < 6; n++) {
                int col = nc + n * 16 + lrow;
                float v = acc[n][j];
                if (col < 128) h1[(size_t)grow * 128 + col] = f2fp8(v);
                else           identity[(size_t)grow * 64 + (col - 128)] = v + bd[col - 128];
            }
        }
    }
}

// ---- MFMA GEMM2: h2 = fp8(out1 @ w2) (LDS version) ----
__global__ __launch_bounds__(256, 1) void k_gemm2(const unsigned short* __restrict__ a_in,
                                                  const unsigned short* __restrict__ w2Ts,
                                                  unsigned char* __restrict__ h2) {
    __shared__ unsigned short As[64][LDA];
    const int t = threadIdx.x;
    const int wid = t >> 6, lane = t & 63;
    const int wr = wid >> 1, wc = wid & 1;
    const int mr = wr * 32, nc = wc * 32;
    const int lrow = lane & 15;
    bf16x8 b[2][4];
#pragma unroll
    for (int n = 0; n < 2; n++)
#pragma unroll
        for (int ki = 0; ki < 4; ki++)
            b[n][ki] = *(const bf16x8*)&w2Ts[(((wc * 2 + n) * 4 + ki) * 64 + lane) * 8];

    for (int tile = blockIdx.x; tile < NT64; tile += GEMM_GRID) {
        const int rb = tile * 64;
        __syncthreads();
        {
#pragma unroll
            for (int i = 0; i < 4; i++) {
                int c = i * 256 + t;
                int row = c >> 4, off = c & 15;
                bf16x8 v = (bf16x8){0, 0, 0, 0, 0, 0, 0, 0};
                if (rb + row < N_NODES)
                    v = *(const bf16x8*)&a_in[(size_t)(rb + row) * 128 + off * 8];
                *(bf16x8*)&As[row][off * 8] = v;
            }
        }
        __syncthreads();
        const int lk = (lane >> 4) * 8;
        bf16x8 a[4][2];
#pragma unroll
        for (int ki = 0; ki < 4; ki++)
#pragma unroll
            for (int m = 0; m < 2; m++)
                a[ki][m] = *(const bf16x8*)&As[mr + m * 16 + lrow][ki * 32 + lk];
        f32x4 acc[2][2];
#pragma unroll
        for (int m = 0; m < 2; m++)
#pragma unroll
            for (int n = 0; n < 2; n++) acc[m][n] = (f32x4){0.f, 0.f, 0.f, 0.f};
#pragma unroll
        for (int n = 0; n < 2; n++)
#pragma unroll
            for (int ki = 0; ki < 4; ki++)
#pragma unroll
                for (int m = 0; m < 2; m++)
                    acc[m][n] = __builtin_amdgcn_mfma_f32_16x16x32_bf16(a[ki][m], b[n][ki], acc[m][n], 0, 0, 0);
        const int crow0 = (lane >> 4) * 4;
#pragma unroll
        for (int m = 0; m < 2; m++) {
#pragma unroll
            for (int j = 0; j < 4; j++) {
                int grow = rb + mr + m * 16 + crow0 + j;
                if (grow >= N_NODES) continue;
#pragma unroll
                for (int n = 0; n < 2; n++) {
                    int col = nc + n * 16 + lrow;
                    h2[(size_t)grow * 64 + col] = f2fp8(acc[m][n][j]);
                }
            }
        }
    }
}

// ---- aggregate 1: depth-2 pipelined gather (csr 2-ahead, gather 1-ahead) ----
// wave = 1 node; 8 groups x 8 lanes; weight-select validity; reduce-scatter +
// distributed epilogue. csr padded with 32 zeroed entries (max idx end+23).
__global__ __launch_bounds__(256) void k_agg1(const unsigned char* __restrict__ h1,
                                              const uint2* __restrict__ csr,
                                              const int* __restrict__ rowptr,
                                              const float* __restrict__ dinv,
                                              const float* __restrict__ b1,
                                              unsigned short* __restrict__ out1) {
    int node = blockIdx.x * 4 + (threadIdx.x >> 6);
    if (node >= N_NODES) return;
    const int lane = threadIdx.x & 63;
    const int g = lane >> 3;   // edge slot 0..7
    const int l = lane & 7;    // feature chunk: [l*16, l*16+16)
    const float di = dinv[node];
    f32x2 a2[8];
#pragma unroll
    for (int i = 0; i < 8; i++) a2[i] = (f32x2){0.f, 0.f};
    const int beg = rowptr[node], end = rowptr[node + 1];
    uint2 ce  = csr[beg + g];
    uint2 ce1 = csr[beg + 8 + g];
    uint4 h = *(const uint4*)&h1[(size_t)ce.x * 128 + l * 16];
    for (int e0 = beg; e0 < end; e0 += 8) {
        uint2 ce2 = csr[e0 + 16 + g];                                   // csr 2-ahead
        uint4 hn = *(const uint4*)&h1[(size_t)ce1.x * 128 + l * 16];    // gather 1-ahead
        float w = (e0 + g < end) ? __uint_as_float(ce.y) : 0.f;
        f32x2 w2 = (f32x2){w, w};
        a2[0] = __builtin_elementwise_fma(w2, __builtin_amdgcn_cvt_pk_f32_fp8(h.x, false), a2[0]);
        a2[1] = __builtin_elementwise_fma(w2, __builtin_amdgcn_cvt_pk_f32_fp8(h.x, true),  a2[1]);
        a2[2] = __builtin_elementwise_fma(w2, __builtin_amdgcn_cvt_pk_f32_fp8(h.y, false), a2[2]);
        a2[3] = __builtin_elementwise_fma(w2, __builtin_amdgcn_cvt_pk_f32_fp8(h.y, true),  a2[3]);
        a2[4] = __builtin_elementwise_fma(w2, __builtin_amdgcn_cvt_pk_f32_fp8(h.z, false), a2[4]);
        a2[5] = __builtin_elementwise_fma(w2, __builtin_amdgcn_cvt_pk_f32_fp8(h.z, true),  a2[5]);
        a2[6] = __builtin_elementwise_fma(w2, __builtin_amdgcn_cvt_pk_f32_fp8(h.w, false), a2[6]);
        a2[7] = __builtin_elementwise_fma(w2, __builtin_amdgcn_cvt_pk_f32_fp8(h.w, true),  a2[7]);
        ce = ce1; ce1 = ce2; h = hn;
    }
    // reduce-scatter butterfly over group bits g2 (xor32), g1 (xor16), g0 (xor8)
    const bool s2 = (lane & 32) != 0;
    const bool s1 = (lane & 16) != 0;
    const bool s0 = (lane & 8) != 0;
    f32x2 rA[4];
#pragma unroll
    for (int j = 0; j < 4; j++) {
        f32x2 keep = s2 ? a2[j + 4] : a2[j];
        f32x2 send = s2 ? a2[j] : a2[j + 4];
        rA[j].x = keep.x + __shfl_xor(send.x, 32);
        rA[j].y = keep.y + __shfl_xor(send.y, 32);
    }
    f32x2 rB[2];
#pragma unroll
    for (int j = 0; j < 2; j++) {
        f32x2 keep = s1 ? rA[j + 2] : rA[j];
        f32x2 send = s1 ? rA[j] : rA[j + 2];
        rB[j].x = keep.x + __shfl_xor(send.x, 16);
        rB[j].y = keep.y + __shfl_xor(send.y, 16);
    }
    f32x2 rC;
    {
        f32x2 keep = s0 ? rB[1] : rB[0];
        f32x2 send = s0 ? rB[0] : rB[1];
        rC.x = keep.x + __shfl_xor(send.x, 8);
        rC.y = keep.y + __shfl_xor(send.y, 8);
    }
    // distributed epilogue: this lane owns feats f0, f0+1 with values rC
    {
        const int f0 = l * 16 + g * 2;
        unsigned hs = (unsigned)*(const unsigned short*)&h1[(size_t)node * 128 + f0];
        f32x2 sv = __builtin_amdgcn_cvt_pk_f32_fp8(hs, false);
        float2 bb = *(const float2*)&b1[f0];
        float t0 = rC.x + di * sv.x;
        float t1 = rC.y + di * sv.y;
        float o0 = lrelu(fmaf(t0, di, bb.x));
        float o1 = lrelu(fmaf(t1, di, bb.y));
        unsigned ov = (unsigned)f2b(o0) | ((unsigned)f2b(o1) << 16);
        *(unsigned*)&out1[(size_t)node * 128 + f0] = ov;
    }
}

// ---- aggregate 2: depth-2 pipelined gather; reduce-scatter; distributed epilogue ----
__global__ __launch_bounds__(256) void k_agg2(const unsigned char* __restrict__ h2,
                                              const uint2* __restrict__ csr,
                                              const int* __restrict__ rowptr,
                                              const float* __restrict__ dinv,
                                              const float* __restrict__ b2,
                                              const float* __restrict__ identity,
                                              float* __restrict__ out) {
    int node = blockIdx.x * 4 + (threadIdx.x >> 6);
    if (node >= N_NODES) return;
    const int lane = threadIdx.x & 63;
    const int g = lane >> 3;
    const int l = lane & 7;    // feature chunk: [l*8, l*8+8)
    const float di = dinv[node];
    f32x2 a2[4];
#pragma unroll
    for (int i = 0; i < 4; i++) a2[i] = (f32x2){0.f, 0.f};
    const int beg = rowptr[node], end = rowptr[node + 1];
    uint2 ce  = csr[beg + g];
    uint2 ce1 = csr[beg + 8 + g];
    uint2 h = *(const uint2*)&h2[(size_t)ce.x * 64 + l * 8];
    for (int e0 = beg; e0 < end; e0 += 8) {
        uint2 ce2 = csr[e0 + 16 + g];
        uint2 hn = *(const uint2*)&h2[(size_t)ce1.x * 64 + l * 8];
        float w = (e0 + g < end) ? __uint_as_float(ce.y) : 0.f;
        f32x2 w2 = (f32x2){w, w};
        a2[0] = __builtin_elementwise_fma(w2, __builtin_amdgcn_cvt_pk_f32_fp8(h.x, false), a2[0]);
        a2[1] = __builtin_elementwise_fma(w2, __builtin_amdgcn_cvt_pk_f32_fp8(h.x, true),  a2[1]);
        a2[2] = __builtin_elementwise_fma(w2, __builtin_amdgcn_cvt_pk_f32_fp8(h.y, false), a2[2]);
        a2[3] = __builtin_elementwise_fma(w2, __builtin_amdgcn_cvt_pk_f32_fp8(h.y, true),  a2[3]);
        ce = ce1; ce1 = ce2; h = hn;
    }
    float a[8];
#pragma unroll
    for (int i = 0; i < 4; i++) { a[2 * i] = a2[i].x; a[2 * i + 1] = a2[i].y; }
    // reduce-scatter over group bits
    const bool s2 = (lane & 32) != 0;
    const bool s1 = (lane & 16) != 0;
    const bool s0 = (lane & 8) != 0;
    float kA[4];
#pragma unroll
    for (int j = 0; j < 4; j++) {
        float keep = s2 ? a[j + 4] : a[j];
        float send = s2 ? a[j] : a[j + 4];
        kA[j] = keep + __shfl_xor(send, 32);
    }
    float kB[2];
#pragma unroll
    for (int j = 0; j < 2; j++) {
        float keep = s1 ? kA[j + 2] : kA[j];
        float send = s1 ? kA[j] : kA[j + 2];
        kB[j] = keep + __shfl_xor(send, 16);
    }
    float kC;
    {
        float keep = s0 ? kB[1] : kB[0];
        float send = s0 ? kB[0] : kB[1];
        kC = keep + __shfl_xor(send, 8);
    }
    // distributed epilogue: this lane owns feat f0 = l*8 + g with value kC
    {
        const int f0 = l * 8 + g;
        unsigned c = (unsigned)h2[(size_t)node * 64 + f0];
        f32x2 svv = __builtin_amdgcn_cvt_pk_f32_fp8(c, false);
        float sv = svv.x;
        float t = kC + di * sv;
        float o = lrelu(fmaf(t, di, b2[f0])) + identity[(size_t)node * 64 + f0];
        out[(size_t)node * 64 + f0] = o;
    }
}

extern "C" void kernel_launch(void* const* d_in, const int* in_sizes, int n_in,
                              void* d_out, int out_size, void* d_ws, size_t ws_size,
                              hipStream_t stream) {
    const float* x  = (const float*)d_in[0];
    const int* eidx = (const int*)d_in[1];
    const float* w1 = (const float*)d_in[2];
    const float* b1 = (const float*)d_in[3];
    const float* w2 = (const float*)d_in[4];
    const float* b2 = (const float*)d_in[5];
    const float* wd = (const float*)d_in[6];
    const float* bd = (const float*)d_in[7];
    const int* src = eidx;
    const int* dst = eidx + N_EDGES;
    float* out = (float*)d_out;

    char* ws = (char*)d_ws;
    size_t off = 0;
    auto take = [&](size_t bytes) -> char* {
        char* p = ws + off;
        off = (off + bytes + 255) & ~(size_t)255;
        return p;
    };
    int* bcnt       = (int*)take((size_t)NBKT * 4);
    int* bbase      = (int*)take((size_t)NBKT * 4);
    int* bcur       = (int*)take((size_t)NBKT * 4);
    int* rowptr     = (int*)take((size_t)(N_NODES + 1) * 4);
    float* dinv     = (float*)take((size_t)N_NODES * 4);
    uint2* csr      = (uint2*)take((size_t)(N_EDGES + 32) * 8);  // +32 zeroed pad entries
    unsigned char* h1   = (unsigned char*)take((size_t)N_NODES * 128);
    unsigned short* out1 = (unsigned short*)take((size_t)N_NODES * 128 * 2);
    unsigned char* h2   = (unsigned char*)take((size_t)N_NODES * 64);
    float* identity = (float*)take((size_t)N_NODES * 64 * 4);
    unsigned short* xf   = (unsigned short*)take((size_t)N_NODES * 128 * 2);
    unsigned short* wTs  = (unsigned short*)take((size_t)3072 * 8 * 2);
    unsigned short* w2Ts = (unsigned short*)take((size_t)1024 * 8 * 2);

    hipMemsetAsync(bcnt, 0, (size_t)NBKT * 4, stream);
    hipMemsetAsync(csr + N_EDGES, 0, 32 * sizeof(uint2), stream);

    k_pre<<<NRG + NBA + 12, 256, 0, stream>>>(x, xf, dst, bcnt, w1, wd, w2, wTs, w2Ts);
    k_bscan<<<1, 512, 0, stream>>>(bcnt, bbase, bcur);
    k_fillA<<<NBA, 256, 0, stream>>>(src, dst, bcur, csr);
    k_fillB1<<<NBKT, 256, 0, stream>>>(csr, bbase, bcnt, rowptr, dinv);
    k_fillB2<<<NBKT, 256, 0, stream>>>(dinv, rowptr, csr);
    k_gemm1f<<<GEMM_GRID, 256, 0, stream>>>(xf, wTs, bd, h1, identity);
    k_agg1<<<(N_NODES + 3) / 4, 256, 0, stream>>>(h1, csr, rowptr, dinv, b1, out1);
    k_gemm2<<<GEMM_GRID, 256, 0, stream>>>(out1, w2Ts, h2);
    k_agg2<<<(N_NODES + 3) / 4, 256, 0, stream>>>(h2, csr, rowptr, dinv, b2, identity, out);
}